// Round 10
// baseline (515.950 us; speedup 1.0000x reference)
//
#include <hip/hip_runtime.h>

typedef unsigned short u16;
typedef unsigned int u32;
typedef __attribute__((ext_vector_type(8))) __bf16 bf16x8;
typedef __attribute__((ext_vector_type(4))) float f32x4;

#define B_ 8
#define S_ 1024
#define D_ 1024
#define H_ 16
#define DK_ 64
#define DFF_ 4096
#define LDQKV 3072

__device__ __forceinline__ float bflo(u32 u) { return __uint_as_float(u << 16); }
__device__ __forceinline__ u16 f2bf(float f) {
    u32 u = __float_as_uint(f);
    u += 0x7fffu + ((u >> 16) & 1u);   // RNE
    return (u16)(u >> 16);
}
// packed f32x2 -> bf16x2 (RNE), one VALU op instead of ~10 (T12 recipe)
__device__ __forceinline__ u32 cvtpk(float lo, float hi) {
    u32 r;
    asm("v_cvt_pk_bf16_f32 %0, %1, %2" : "=v"(r) : "v"(lo), "v"(hi));
    return r;
}

// async global->LDS DMA, 16B per lane; LDS dest = wave-uniform base + lane*16
__device__ __forceinline__ void gl2lds16(const u16* g, u16* l) {
    __builtin_amdgcn_global_load_lds(
        (const __attribute__((address_space(1))) void*)g,
        (__attribute__((address_space(3))) void*)l, 16, 0, 0);
}

// ---------------------------------------------------------------------------
// PREP: one dispatch fusing LN1 (blocks 0..M-1, one row each) with the
// fp32->bf16 conversion of all 6 weights + 6 bias regions (blocks >= M,
// grid-strided, 8 elems/thread via 2x float4 + cvt_pk). Validated r9.
// ---------------------------------------------------------------------------
struct PrepTbl {
    const void* src[12];
    u16* dst[12];
    int nch[12];   // region length in 8-elem chunks
    int total;     // sum of nch
    int convBlocks;
};
__global__ __launch_bounds__(256) void prep_kernel(PrepTbl tb,
                                                   const float* __restrict__ x,
                                                   const float* __restrict__ g1,
                                                   const float* __restrict__ be1,
                                                   u16* __restrict__ ln_out) {
    const int t = threadIdx.x;
    if ((int)blockIdx.x < B_ * S_) {
        // ---- LN1 row ----
        const int row = blockIdx.x;
        const float* p = x + (size_t)row * D_ + t * 4;
        float4 f = *(const float4*)p;
        float s = f.x + f.y + f.z + f.w;
        float sq = f.x * f.x + f.y * f.y + f.z * f.z + f.w * f.w;
#pragma unroll
        for (int m = 1; m < 64; m <<= 1) {
            s += __shfl_xor(s, m, 64);
            sq += __shfl_xor(sq, m, 64);
        }
        __shared__ float ss[4], sqs[4];
        const int w = t >> 6;
        if ((t & 63) == 0) { ss[w] = s; sqs[w] = sq; }
        __syncthreads();
        s = ss[0] + ss[1] + ss[2] + ss[3];
        sq = sqs[0] + sqs[1] + sqs[2] + sqs[3];
        const float mu = s * (1.f / 1024.f);
        float var = (sq - 1024.f * mu * mu) * (1.f / 1023.f);
        var = fmaxf(var, 0.f);
        const float rstd = rsqrtf(var + 1e-5f);
        const float gm = g1[0], bt = be1[0];
        uint2 uo;
        uo.x = cvtpk(gm * (f.x - mu) * rstd + bt, gm * (f.y - mu) * rstd + bt);
        uo.y = cvtpk(gm * (f.z - mu) * rstd + bt, gm * (f.w - mu) * rstd + bt);
        *(uint2*)(ln_out + (size_t)row * D_ + t * 4) = uo;
        return;
    }
    // ---- conversion slice ----
    const int bid = blockIdx.x - B_ * S_;
    for (int idx = bid * 256 + t; idx < tb.total; idx += tb.convBlocks * 256) {
        int i = idx, j = 0;
#pragma unroll
        for (int k = 0; k < 11; ++k) {
            if (i >= tb.nch[j]) { i -= tb.nch[j]; ++j; }
        }
        const float4* sp = (const float4*)tb.src[j] + 2 * (size_t)i;
        float4 a = sp[0], b = sp[1];
        uint4 o;
        o.x = cvtpk(a.x, a.y);
        o.y = cvtpk(a.z, a.w);
        o.z = cvtpk(b.x, b.y);
        o.w = cvtpk(b.z, b.w);
        *((uint4*)tb.dst[j] + i) = o;
    }
}

// ---------------------------------------------------------------------------
// LayerNorm (ddof=1, scalar fp32 gamma/beta), fp32 input. One block per row.
// ---------------------------------------------------------------------------
__global__ __launch_bounds__(256) void ln_kernel(const float* __restrict__ in,
                                                 const float* __restrict__ gs,
                                                 const float* __restrict__ bs,
                                                 u16* __restrict__ out) {
    const int row = blockIdx.x, t = threadIdx.x;
    const float* p = in + (size_t)row * D_ + t * 4;
    float4 f = *(const float4*)p;
    float s = f.x + f.y + f.z + f.w;
    float sq = f.x * f.x + f.y * f.y + f.z * f.z + f.w * f.w;
#pragma unroll
    for (int m = 1; m < 64; m <<= 1) {
        s += __shfl_xor(s, m, 64);
        sq += __shfl_xor(sq, m, 64);
    }
    __shared__ float ss[4], sqs[4];
    const int w = t >> 6;
    if ((t & 63) == 0) { ss[w] = s; sqs[w] = sq; }
    __syncthreads();
    s = ss[0] + ss[1] + ss[2] + ss[3];
    sq = sqs[0] + sqs[1] + sqs[2] + sqs[3];
    const float mu = s * (1.f / 1024.f);
    float var = (sq - 1024.f * mu * mu) * (1.f / 1023.f);
    var = fmaxf(var, 0.f);
    const float rstd = rsqrtf(var + 1e-5f);
    const float gm = gs[0], bt = bs[0];
    uint2 uo;
    uo.x = cvtpk(gm * (f.x - mu) * rstd + bt, gm * (f.y - mu) * rstd + bt);
    uo.y = cvtpk(gm * (f.z - mu) * rstd + bt, gm * (f.w - mu) * rstd + bt);
    *(uint2*)(out + (size_t)row * D_ + t * 4) = uo;
}

// ---------------------------------------------------------------------------
// GEMM 128x128, 2-barrier, 4 blocks/CU (proven: FFN2 ~82-90us, O-proj ~26us).
// Cross-block TLP hides the per-tile vmcnt(0) drain. ni-inner epilogue.
// RES: 0 none, 2 fp32. OUTF: 0 bf16, 1 fp32.
// ---------------------------------------------------------------------------
template <int RELU, int RES, int OUTF>
__global__ __launch_bounds__(256, 4) void gemm_bt(const u16* __restrict__ A,
                                                  const u16* __restrict__ W,
                                                  const u16* __restrict__ bias,
                                                  const void* __restrict__ res,
                                                  void* __restrict__ out,
                                                  int M, int N, int K) {
    __shared__ __align__(16) u16 As[128 * 64];
    __shared__ __align__(16) u16 Bs[128 * 64];
    const int t = threadIdx.x;
    const int lane = t & 63, w = t >> 6;
    const int wm = w >> 1, wn = w & 1;

    const int nx = N >> 7;
    const int gsz = nx << 3;
    const int id = blockIdx.x;
    const int grp = id / gsz;
    const int rem = id - grp * gsz;
    const int m0 = ((grp << 3) + (rem & 7)) << 7;
    const int n0 = (rem >> 3) << 7;

    f32x4 acc[4][4];
#pragma unroll
    for (int mi = 0; mi < 4; ++mi)
#pragma unroll
        for (int ni = 0; ni < 4; ++ni) acc[mi][ni] = (f32x4){0.f, 0.f, 0.f, 0.f};

    const int r8 = lane >> 3, s8 = lane & 7;
    const int cg = s8 ^ r8;
    const u16* Ag = A + (size_t)(m0 + w * 8 + r8) * K + cg * 8;
    const u16* Bg = W + (size_t)(n0 + w * 8 + r8) * K + cg * 8;
    const size_t rI = (size_t)32 * K;
    u16* Asd = &As[(w * 8) * 64];
    u16* Bsd = &Bs[(w * 8) * 64];

    const int c = lane & 15, g = lane >> 4;
    const u16* As_r = &As[(wm * 64 + c) * 64];
    const u16* Bs_r = &Bs[(wn * 64 + c) * 64];
    const int sl0 = (g ^ (c & 7)) * 8;
    const int sl1 = ((4 + g) ^ (c & 7)) * 8;

    for (int kt = 0; kt < K; kt += 64) {
        __syncthreads();
        gl2lds16(Ag, Asd);
        gl2lds16(Ag + rI, Asd + 32 * 64);
        gl2lds16(Ag + 2 * rI, Asd + 64 * 64);
        gl2lds16(Ag + 3 * rI, Asd + 96 * 64);
        gl2lds16(Bg, Bsd);
        gl2lds16(Bg + rI, Bsd + 32 * 64);
        gl2lds16(Bg + 2 * rI, Bsd + 64 * 64);
        gl2lds16(Bg + 3 * rI, Bsd + 96 * 64);
        Ag += 64; Bg += 64;
        __syncthreads();
#pragma unroll
        for (int kc = 0; kc < 2; ++kc) {
            const int sl = kc ? sl1 : sl0;
            bf16x8 af[4], bfr[4];
#pragma unroll
            for (int i = 0; i < 4; ++i) {
                af[i] = *(const bf16x8*)(As_r + i * 16 * 64 + sl);
                bfr[i] = *(const bf16x8*)(Bs_r + i * 16 * 64 + sl);
            }
#pragma unroll
            for (int mi = 0; mi < 4; ++mi)
#pragma unroll
                for (int ni = 0; ni < 4; ++ni)
                    acc[mi][ni] = __builtin_amdgcn_mfma_f32_16x16x32_bf16(af[mi], bfr[ni], acc[mi][ni], 0, 0, 0);
        }
    }

    const int qd = lane >> 4, cl = lane & 15;
    float bv[4];
#pragma unroll
    for (int ni = 0; ni < 4; ++ni)
        bv[ni] = bflo((u32)bias[n0 + wn * 64 + ni * 16 + cl]);
#pragma unroll
    for (int mi = 0; mi < 4; ++mi) {
#pragma unroll
        for (int j = 0; j < 4; ++j) {
            const int row = m0 + wm * 64 + mi * 16 + qd * 4 + j;
#pragma unroll
            for (int ni = 0; ni < 4; ++ni) {
                const int col = n0 + wn * 64 + ni * 16 + cl;
                float vv = acc[mi][ni][j] + bv[ni];
                if (RELU) vv = fmaxf(vv, 0.f);
                if (RES == 2) vv += ((const float*)res)[(size_t)row * N + col];
                if (OUTF == 1)
                    ((float*)out)[(size_t)row * N + col] = vv;
                else
                    ((u16*)out)[(size_t)row * N + col] = f2bf(vv);
            }
        }
    }
}

// ---------------------------------------------------------------------------
// GEMM 256x256, 2-PHASE counted-vmcnt pipeline (validated r6/r7/r9 config;
// r8's finer 4-subphase grain REGRESSED — do not re-split).
// 12 ds_read_b128 feed 32 MFMA per phase (0.375 reads/MFMA).
// Ledger: ph0 stages (kt+1).{A1,B1}[4] -> buf^1; ph1 stages (kt+2).{A0,B0}[4]
// -> buf[cur].kc0; tile-end vmcnt(4) == tile kt+1 fully landed. Tail vmcnt(0).
// Conflict-free slot XOR (r3): slot = chunk ^ ((row>>1)&3).
// ---------------------------------------------------------------------------
template <int RELU>
__global__ __launch_bounds__(512, 2) void gemm256(const u16* __restrict__ A,
                                                  const u16* __restrict__ W,
                                                  const u16* __restrict__ bias,
                                                  u16* __restrict__ out,
                                                  int M, int N, int K) {
    __shared__ __align__(16) u16 As[2][2][256 * 32];
    __shared__ __align__(16) u16 Bs[2][2][256 * 32];
    const int t = threadIdx.x;
    const int lane = t & 63, w = t >> 6;
    const int wm = w >> 2, wn = w & 3;

    const int nx = N >> 8;
    const int gsz = nx << 3;
    const int id = blockIdx.x;
    const int grp = id / gsz;
    const int rem = id - grp * gsz;
    const int m0 = ((grp << 3) + (rem & 7)) << 8;
    const int n0 = (rem >> 3) << 8;

    f32x4 acc[8][4];
#pragma unroll
    for (int mi = 0; mi < 8; ++mi)
#pragma unroll
        for (int ni = 0; ni < 4; ++ni) acc[mi][ni] = (f32x4){0.f, 0.f, 0.f, 0.f};

    const int vr = lane >> 2, vs = lane & 3;
    const int cgs = vs ^ ((vr >> 1) & 3);
    const u16* Asrc = A + (size_t)(m0 + w * 16 + vr) * K + cgs * 8;
    const u16* Bsrc = W + (size_t)(n0 + w * 16 + vr) * K + cgs * 8;
    const size_t rI = (size_t)128 * K;

    auto stageA = [&](int p, int kc, int tk) {
        u16* d = &As[p][kc][(w * 16) * 32];
        const u16* s = Asrc + (size_t)tk * 64 + kc * 32;
        gl2lds16(s, d);
        gl2lds16(s + rI, d + 128 * 32);
    };
    auto stageB = [&](int p, int kc, int tk) {
        u16* d = &Bs[p][kc][(w * 16) * 32];
        const u16* s = Bsrc + (size_t)tk * 64 + kc * 32;
        gl2lds16(s, d);
        gl2lds16(s + rI, d + 128 * 32);
    };

    const int c = lane & 15, g = lane >> 4;
    const int sx = (g ^ ((c >> 1) & 3)) << 3;

    const int nt = K >> 6;
    stageA(0, 0, 0); stageB(0, 0, 0);
    stageA(0, 1, 0); stageB(0, 1, 0);
    stageA(1, 0, 1); stageB(1, 0, 1);
    asm volatile("s_waitcnt vmcnt(4)" ::: "memory");
    __builtin_amdgcn_s_barrier();
    __builtin_amdgcn_sched_barrier(0);

    int cur = 0;
    for (int kt = 0; kt < nt; ++kt) {
        // ---- phase 0: kc = 0 ----
        {
            bf16x8 af[8], bfv[4];
            const u16* Ab = &As[cur][0][0];
            const u16* Bb = &Bs[cur][0][0];
#pragma unroll
            for (int i = 0; i < 8; ++i)
                af[i] = *(const bf16x8*)(Ab + (wm * 128 + i * 16 + c) * 32 + sx);
#pragma unroll
            for (int i = 0; i < 4; ++i)
                bfv[i] = *(const bf16x8*)(Bb + (wn * 64 + i * 16 + c) * 32 + sx);
            if (kt + 1 < nt) { stageA(cur ^ 1, 1, kt + 1); stageB(cur ^ 1, 1, kt + 1); }
            __builtin_amdgcn_s_barrier();
            __builtin_amdgcn_s_setprio(1);
#pragma unroll
            for (int mi = 0; mi < 8; ++mi)
#pragma unroll
                for (int ni = 0; ni < 4; ++ni)
                    acc[mi][ni] = __builtin_amdgcn_mfma_f32_16x16x32_bf16(
                        af[mi], bfv[ni], acc[mi][ni], 0, 0, 0);
            __builtin_amdgcn_s_setprio(0);
            __builtin_amdgcn_s_barrier();   // kc0 reads done -> ph1 may overwrite
            __builtin_amdgcn_sched_barrier(0);
        }
        // ---- phase 1: kc = 1 ----
        {
            bf16x8 af[8], bfv[4];
            const u16* Ab = &As[cur][1][0];
            const u16* Bb = &Bs[cur][1][0];
#pragma unroll
            for (int i = 0; i < 8; ++i)
                af[i] = *(const bf16x8*)(Ab + (wm * 128 + i * 16 + c) * 32 + sx);
#pragma unroll
            for (int i = 0; i < 4; ++i)
                bfv[i] = *(const bf16x8*)(Bb + (wn * 64 + i * 16 + c) * 32 + sx);
            if (kt + 2 < nt) { stageA(cur, 0, kt + 2); stageB(cur, 0, kt + 2); }
            __builtin_amdgcn_s_barrier();
            __builtin_amdgcn_s_setprio(1);
#pragma unroll
            for (int mi = 0; mi < 8; ++mi)
#pragma unroll
                for (int ni = 0; ni < 4; ++ni)
                    acc[mi][ni] = __builtin_amdgcn_mfma_f32_16x16x32_bf16(
                        af[mi], bfv[ni], acc[mi][ni], 0, 0, 0);
            __builtin_amdgcn_s_setprio(0);
        }
        // ---- tile end: certify tile kt+1 ----
        if (kt < nt - 2)
            asm volatile("s_waitcnt vmcnt(4)" ::: "memory");
        else
            asm volatile("s_waitcnt vmcnt(0)" ::: "memory");
        __builtin_amdgcn_s_barrier();
        __builtin_amdgcn_sched_barrier(0);
        cur ^= 1;
    }

    // epilogue: ni innermost -> full 128B line dirty in 4 consecutive stores
#pragma unroll
    for (int mi = 0; mi < 8; ++mi) {
#pragma unroll
        for (int j = 0; j < 4; ++j) {
            const int row = m0 + wm * 128 + mi * 16 + g * 4 + j;
#pragma unroll
            for (int ni = 0; ni < 4; ++ni) {
                const int col = n0 + wn * 64 + ni * 16 + c;
                float vv = acc[mi][ni][j] + bflo((u32)bias[col]);
                if (RELU) vv = fmaxf(vv, 0.f);
                out[(size_t)row * N + col] = f2bf(vv);
            }
        }
    }
}

// ---------------------------------------------------------------------------
// MFMA flash attention, round 16: occupancy doubled. r9 counters showed the
// kernel GRID-limited at 2 blocks/CU (OccupancyPercent 19, VALUBusy 53,
// MfmaUtil 17): the serial QK->softmax->PV chain had only 2 waves/SIMD to
// overlap. Now QBLK=128 (wave owns 32 q-rows, ni in 0..1), grid.x = S/128=8
// -> 1024 blocks = 4 blocks/CU = 4 waves/SIMD. LDS 32KB/block (Ks 8K +
// VsT 8K + 4x Pw 4K); VGPR ~116 (acc_o 32 + acc_s 32 + qfrag 16 + temps)
// fits launch_bounds(256,4). K/V re-staged 8x per (b,h) but 256KB/head is
// L2-resident. Same swizzles/cvt_pk/rescale-skip as the validated structure.
// ---------------------------------------------------------------------------
__global__ __launch_bounds__(256, 4) void attn_mfma(const u16* __restrict__ QKV,
                                                    u16* __restrict__ O) {
    __shared__ __align__(16) u16 lds[4096 + 4096 + 4 * 2048];  // Ks | VsT | P x4
    u16* Ks = lds;
    u16* VsT = lds + 4096;

    const int t = threadIdx.x;
    const int lane = t & 63, w = t >> 6;
    u16* Pw = lds + 8192 + w * 2048;
    const int b = blockIdx.y >> 4, h = blockIdx.y & 15;
    const int q_base = blockIdx.x * 128 + w * 32;
    const int c = lane & 15, g = lane >> 4;
    const int c7 = c & 7;
    const float SC = 0.18033688011112042f;  // (1/8)*log2(e)

    bf16x8 qfrag[2][2];
#pragma unroll
    for (int ni = 0; ni < 2; ++ni)
#pragma unroll
        for (int kc = 0; kc < 2; ++kc)
            qfrag[ni][kc] = *(const bf16x8*)(QKV + (size_t)(b * S_ + q_base + 16 * ni + c) * LDQKV +
                                             h * 64 + kc * 32 + 8 * g);

    f32x4 acc_o[4][2];
#pragma unroll
    for (int mi = 0; mi < 4; ++mi)
#pragma unroll
        for (int ni = 0; ni < 2; ++ni) acc_o[mi][ni] = (f32x4){0.f, 0.f, 0.f, 0.f};
    float m_st[2] = {-1e30f, -1e30f};  // raw (unscaled) units
    float l_st[2] = {0.f, 0.f};

    const size_t kbase = (size_t)(b * S_) * LDQKV + 1024 + h * 64;
    const size_t vbase = (size_t)(b * S_) * LDQKV + 2048 + h * 64;

    const int r8 = lane >> 3, s8 = lane & 7;
    const int cgk = s8 ^ r8;
    const u16* Kg = QKV + kbase + (size_t)(w * 8 + r8) * LDQKV + cgk * 8;
    u16* Ksd = &Ks[(w * 8) * 64];
    const size_t rIk = (size_t)32 * LDQKV;

    const int vr = t >> 3, vdq = t & 7;
    const u16* Vg = QKV + vbase + (size_t)(2 * vr) * LDQKV + vdq * 8;

    int vfx[4];
#pragma unroll
    for (int mi = 0; mi < 4; ++mi) vfx[mi] = c7 ^ ((2 * mi + (c >> 3)) & 7);

    for (int kt = 0; kt < 16; ++kt) {
        __syncthreads();
        gl2lds16(Kg, Ksd);
        gl2lds16(Kg + rIk, Ksd + 32 * 64);
        Kg += (size_t)64 * LDQKV;
        {
            uint4 a = *(const uint4*)Vg;
            uint4 bb = *(const uint4*)(Vg + LDQKV);
            Vg += (size_t)64 * LDQKV;
            const u32 aw[4] = {a.x, a.y, a.z, a.w};
            const u32 bw[4] = {bb.x, bb.y, bb.z, bb.w};
#pragma unroll
            for (int i = 0; i < 8; ++i) {
                u32 wv;
                if (i & 1)
                    wv = (aw[i >> 1] >> 16) | (bw[i >> 1] & 0xffff0000u);
                else
                    wv = (aw[i >> 1] & 0xffffu) | (bw[i >> 1] << 16);
                const int d = vdq * 8 + i;
                *(u32*)&VsT[d * 64 + (((vr >> 2) ^ (i ^ vdq)) << 3) + ((vr & 3) << 1)] = wv;
            }
        }
        __syncthreads();

        f32x4 acc_s[4][2];
#pragma unroll
        for (int mi = 0; mi < 4; ++mi)
#pragma unroll
            for (int ni = 0; ni < 2; ++ni) acc_s[mi][ni] = (f32x4){0.f, 0.f, 0.f, 0.f};
        __builtin_amdgcn_s_setprio(1);
#pragma unroll
        for (int kc = 0; kc < 2; ++kc) {
            bf16x8 kf[4];
#pragma unroll
            for (int mi = 0; mi < 4; ++mi)
                kf[mi] = *(const bf16x8*)&Ks[(16 * mi + c) * 64 + (((kc * 4 + g) ^ c7) << 3)];
#pragma unroll
            for (int mi = 0; mi < 4; ++mi)
#pragma unroll
                for (int ni = 0; ni < 2; ++ni)
                    acc_s[mi][ni] = __builtin_amdgcn_mfma_f32_16x16x32_bf16(
                        kf[mi], qfrag[ni][kc], acc_s[mi][ni], 0, 0, 0);
        }
        __builtin_amdgcn_s_setprio(0);

        float alpha[2];
        bool resc[2];
#pragma unroll
        for (int ni = 0; ni < 2; ++ni) {
            float mx = -1e30f;
#pragma unroll
            for (int mi = 0; mi < 4; ++mi) {
#pragma unroll
                for (int j = 0; j < 4; ++j) mx = fmaxf(mx, acc_s[mi][ni][j]);
            }
            mx = fmaxf(mx, __shfl_xor(mx, 16, 64));
            mx = fmaxf(mx, __shfl_xor(mx, 32, 64));
            const float mo = m_st[ni];
            const float mn = fmaxf(mo, mx);
            resc[ni] = __any(mn > mo);
            if (resc[ni]) {
                alpha[ni] = exp2f((mo - mn) * SC);
                m_st[ni] = mn;
            } else {
                alpha[ni] = 1.f;
            }
            const float nms = m_st[ni] * SC;
            float sum = 0.f;
#pragma unroll
            for (int mi = 0; mi < 4; ++mi) {
                const float p0 = exp2f(fmaf(acc_s[mi][ni][0], SC, -nms));
                const float p1 = exp2f(fmaf(acc_s[mi][ni][1], SC, -nms));
                const float p2 = exp2f(fmaf(acc_s[mi][ni][2], SC, -nms));
                const float p3 = exp2f(fmaf(acc_s[mi][ni][3], SC, -nms));
                sum += (p0 + p1) + (p2 + p3);
                uint2 pk;
                pk.x = cvtpk(p0, p1);
                pk.y = cvtpk(p2, p3);
                *(uint2*)&Pw[(16 * ni + c) * 64 +
                             ((((2 * mi + (g >> 1)) ^ c7) << 3) + ((g & 1) << 2))] = pk;
            }
            sum += __shfl_xor(sum, 16, 64);
            sum += __shfl_xor(sum, 32, 64);
            l_st[ni] = (resc[ni] ? l_st[ni] * alpha[ni] : l_st[ni]) + sum;
        }
#pragma unroll
        for (int ni = 0; ni < 2; ++ni) {
            if (resc[ni]) {
#pragma unroll
                for (int mi = 0; mi < 4; ++mi) {
#pragma unroll
                    for (int j = 0; j < 4; ++j) acc_o[mi][ni][j] *= alpha[ni];
                }
            }
        }

        __builtin_amdgcn_s_setprio(1);
#pragma unroll
        for (int kc = 0; kc < 2; ++kc) {
            bf16x8 vf[4], pf[2];
#pragma unroll
            for (int mi = 0; mi < 4; ++mi)
                vf[mi] = *(const bf16x8*)&VsT[(16 * mi + c) * 64 + (((kc * 4 + g) ^ vfx[mi]) << 3)];
#pragma unroll
            for (int ni = 0; ni < 2; ++ni)
                pf[ni] = *(const bf16x8*)&Pw[(16 * ni + c) * 64 + (((kc * 4 + g) ^ c7) << 3)];
#pragma unroll
            for (int mi = 0; mi < 4; ++mi)
#pragma unroll
                for (int ni = 0; ni < 2; ++ni)
                    acc_o[mi][ni] = __builtin_amdgcn_mfma_f32_16x16x32_bf16(
                        vf[mi], pf[ni], acc_o[mi][ni], 0, 0, 0);
        }
        __builtin_amdgcn_s_setprio(0);
    }

#pragma unroll
    for (int ni = 0; ni < 2; ++ni) {
        const float inv_l = 1.f / l_st[ni];
        u16* op = O + (size_t)(b * S_ + q_base + 16 * ni + c) * D_ + h * 64;
#pragma unroll
        for (int mi = 0; mi < 4; ++mi) {
            uint2 uo;
            uo.x = cvtpk(acc_o[mi][ni][0] * inv_l, acc_o[mi][ni][1] * inv_l);
            uo.y = cvtpk(acc_o[mi][ni][2] * inv_l, acc_o[mi][ni][3] * inv_l);
            *(uint2*)(op + 16 * mi + 4 * g) = uo;
        }
    }
}

// ---------------------------------------------------------------------------
extern "C" void kernel_launch(void* const* d_in, const int* in_sizes, int n_in,
                              void* d_out, int out_size, void* d_ws, size_t ws_size,
                              hipStream_t stream) {
    (void)in_sizes; (void)n_in; (void)out_size; (void)ws_size;
    char* ws = (char*)d_ws;
    const size_t MB = 1ull << 20;
    const size_t KB = 1024;
    u16* wqkv = (u16*)(ws + 16 * MB);       // 6 MB  [3072][1024]
    u16* won  = (u16*)(ws + 22 * MB);       // 2 MB
    u16* w1n  = (u16*)(ws + 24 * MB);       // 8 MB
    u16* w2n  = (u16*)(ws + 32 * MB);       // 8 MB
    u16* bqkv = (u16*)(ws + 40 * MB);       // 6 KB
    u16* bon  = (u16*)(ws + 40 * MB + 64 * KB);
    u16* b1n  = (u16*)(ws + 40 * MB + 128 * KB);
    u16* b2n  = (u16*)(ws + 40 * MB + 192 * KB);
    u16* h1   = (u16*)(ws + 48 * MB);       // 16 MB: ln1 out; attn out
    u16* qkv  = (u16*)(ws + 64 * MB);       // 48 MB: fused QKV
    float* x2 = (float*)(ws + 64 * MB);     // 32 MB, overlays qkv (dead after attn)
    u16* h2   = (u16*)(ws + 96 * MB);       // 16 MB, overlays qkv tail
    u16* f1   = (u16*)(ws + 112 * MB);      // 64 MB -> total 176 MB

    const int M = B_ * S_;  // 8192
    const int CONV_BLOCKS = 2048;

    // prep: LN1 (M blocks) + all 12 fp32->bf16 conversions (grid-strided)
    {
        PrepTbl tb;
        tb.src[0]  = d_in[2];  tb.dst[0]  = wqkv;               tb.nch[0]  = D_ * D_ / 8;
        tb.src[1]  = d_in[4];  tb.dst[1]  = wqkv + D_ * D_;     tb.nch[1]  = D_ * D_ / 8;
        tb.src[2]  = d_in[6];  tb.dst[2]  = wqkv + 2 * D_ * D_; tb.nch[2]  = D_ * D_ / 8;
        tb.src[3]  = d_in[8];  tb.dst[3]  = won;                tb.nch[3]  = D_ * D_ / 8;
        tb.src[4]  = d_in[10]; tb.dst[4]  = w1n;                tb.nch[4]  = DFF_ * D_ / 8;
        tb.src[5]  = d_in[12]; tb.dst[5]  = w2n;                tb.nch[5]  = D_ * DFF_ / 8;
        tb.src[6]  = d_in[3];  tb.dst[6]  = bqkv;               tb.nch[6]  = D_ / 8;
        tb.src[7]  = d_in[5];  tb.dst[7]  = bqkv + D_;          tb.nch[7]  = D_ / 8;
        tb.src[8]  = d_in[7];  tb.dst[8]  = bqkv + 2 * D_;      tb.nch[8]  = D_ / 8;
        tb.src[9]  = d_in[9];  tb.dst[9]  = bon;                tb.nch[9]  = D_ / 8;
        tb.src[10] = d_in[11]; tb.dst[10] = b1n;                tb.nch[10] = DFF_ / 8;
        tb.src[11] = d_in[13]; tb.dst[11] = b2n;                tb.nch[11] = D_ / 8;
        tb.total = (4 * D_ * D_ + 2 * DFF_ * D_ + 5 * D_ + DFF_) / 8;
        tb.convBlocks = CONV_BLOCKS;
        prep_kernel<<<M + CONV_BLOCKS, 256, 0, stream>>>(
            tb, (const float*)d_in[0], (const float*)d_in[14],
            (const float*)d_in[15], h1);
    }

    // QKV: 256^2 2-phase pipeline (grid 384)
    gemm256<0><<<(LDQKV / 256) * (M / 256), 512, 0, stream>>>(h1, wqkv, bqkv, qkv, M, LDQKV, D_);
    attn_mfma<<<dim3(S_ / 128, B_ * H_), 256, 0, stream>>>(qkv, h1);
    // O-proj: residual = original x (fp32), fp32 out
    gemm_bt<0, 2, 1><<<(D_ / 128) * (M / 128), 256, 0, stream>>>(h1, won, bon, d_in[0], x2, M, D_, D_);
    ln_kernel<<<M, 256, 0, stream>>>(x2, (const float*)d_in[16], (const float*)d_in[17], h2);
    gemm256<1><<<(DFF_ / 256) * (M / 256), 512, 0, stream>>>(h2, w1n, b1n, f1, M, DFF_, D_);
    gemm_bt<0, 2, 1><<<(D_ / 128) * (M / 128), 256, 0, stream>>>(f1, w2n, b2n, x2, d_out, M, D_, DFF_);
}

// Round 11
// 473.964 us; speedup vs baseline: 1.0886x; 1.0886x over previous
//
#include <hip/hip_runtime.h>

typedef unsigned short u16;
typedef unsigned int u32;
typedef __attribute__((ext_vector_type(8))) __bf16 bf16x8;
typedef __attribute__((ext_vector_type(4))) float f32x4;

#define B_ 8
#define S_ 1024
#define D_ 1024
#define H_ 16
#define DK_ 64
#define DFF_ 4096
#define LDQKV 3072

__device__ __forceinline__ float bflo(u32 u) { return __uint_as_float(u << 16); }
__device__ __forceinline__ u16 f2bf(float f) {
    u32 u = __float_as_uint(f);
    u += 0x7fffu + ((u >> 16) & 1u);   // RNE
    return (u16)(u >> 16);
}
// packed f32x2 -> bf16x2 (RNE), one VALU op instead of ~10 (T12 recipe)
__device__ __forceinline__ u32 cvtpk(float lo, float hi) {
    u32 r;
    asm("v_cvt_pk_bf16_f32 %0, %1, %2" : "=v"(r) : "v"(lo), "v"(hi));
    return r;
}

// async global->LDS DMA, 16B per lane; LDS dest = wave-uniform base + lane*16
__device__ __forceinline__ void gl2lds16(const u16* g, u16* l) {
    __builtin_amdgcn_global_load_lds(
        (const __attribute__((address_space(1))) void*)g,
        (__attribute__((address_space(3))) void*)l, 16, 0, 0);
}

// ---------------------------------------------------------------------------
// PREP: one dispatch fusing LN1 (blocks 0..M-1, one row each) with the
// fp32->bf16 conversion of all 6 weights + 6 bias regions (blocks >= M,
// grid-strided, 8 elems/thread via 2x float4 + cvt_pk). Validated r9.
// ---------------------------------------------------------------------------
struct PrepTbl {
    const void* src[12];
    u16* dst[12];
    int nch[12];   // region length in 8-elem chunks
    int total;     // sum of nch
    int convBlocks;
};
__global__ __launch_bounds__(256) void prep_kernel(PrepTbl tb,
                                                   const float* __restrict__ x,
                                                   const float* __restrict__ g1,
                                                   const float* __restrict__ be1,
                                                   u16* __restrict__ ln_out) {
    const int t = threadIdx.x;
    if ((int)blockIdx.x < B_ * S_) {
        // ---- LN1 row ----
        const int row = blockIdx.x;
        const float* p = x + (size_t)row * D_ + t * 4;
        float4 f = *(const float4*)p;
        float s = f.x + f.y + f.z + f.w;
        float sq = f.x * f.x + f.y * f.y + f.z * f.z + f.w * f.w;
#pragma unroll
        for (int m = 1; m < 64; m <<= 1) {
            s += __shfl_xor(s, m, 64);
            sq += __shfl_xor(sq, m, 64);
        }
        __shared__ float ss[4], sqs[4];
        const int w = t >> 6;
        if ((t & 63) == 0) { ss[w] = s; sqs[w] = sq; }
        __syncthreads();
        s = ss[0] + ss[1] + ss[2] + ss[3];
        sq = sqs[0] + sqs[1] + sqs[2] + sqs[3];
        const float mu = s * (1.f / 1024.f);
        float var = (sq - 1024.f * mu * mu) * (1.f / 1023.f);
        var = fmaxf(var, 0.f);
        const float rstd = rsqrtf(var + 1e-5f);
        const float gm = g1[0], bt = be1[0];
        uint2 uo;
        uo.x = cvtpk(gm * (f.x - mu) * rstd + bt, gm * (f.y - mu) * rstd + bt);
        uo.y = cvtpk(gm * (f.z - mu) * rstd + bt, gm * (f.w - mu) * rstd + bt);
        *(uint2*)(ln_out + (size_t)row * D_ + t * 4) = uo;
        return;
    }
    // ---- conversion slice ----
    const int bid = blockIdx.x - B_ * S_;
    for (int idx = bid * 256 + t; idx < tb.total; idx += tb.convBlocks * 256) {
        int i = idx, j = 0;
#pragma unroll
        for (int k = 0; k < 11; ++k) {
            if (i >= tb.nch[j]) { i -= tb.nch[j]; ++j; }
        }
        const float4* sp = (const float4*)tb.src[j] + 2 * (size_t)i;
        float4 a = sp[0], b = sp[1];
        uint4 o;
        o.x = cvtpk(a.x, a.y);
        o.y = cvtpk(a.z, a.w);
        o.z = cvtpk(b.x, b.y);
        o.w = cvtpk(b.z, b.w);
        *((uint4*)tb.dst[j] + i) = o;
    }
}

// ---------------------------------------------------------------------------
// LayerNorm (ddof=1, scalar fp32 gamma/beta), fp32 input. One block per row.
// ---------------------------------------------------------------------------
__global__ __launch_bounds__(256) void ln_kernel(const float* __restrict__ in,
                                                 const float* __restrict__ gs,
                                                 const float* __restrict__ bs,
                                                 u16* __restrict__ out) {
    const int row = blockIdx.x, t = threadIdx.x;
    const float* p = in + (size_t)row * D_ + t * 4;
    float4 f = *(const float4*)p;
    float s = f.x + f.y + f.z + f.w;
    float sq = f.x * f.x + f.y * f.y + f.z * f.z + f.w * f.w;
#pragma unroll
    for (int m = 1; m < 64; m <<= 1) {
        s += __shfl_xor(s, m, 64);
        sq += __shfl_xor(sq, m, 64);
    }
    __shared__ float ss[4], sqs[4];
    const int w = t >> 6;
    if ((t & 63) == 0) { ss[w] = s; sqs[w] = sq; }
    __syncthreads();
    s = ss[0] + ss[1] + ss[2] + ss[3];
    sq = sqs[0] + sqs[1] + sqs[2] + sqs[3];
    const float mu = s * (1.f / 1024.f);
    float var = (sq - 1024.f * mu * mu) * (1.f / 1023.f);
    var = fmaxf(var, 0.f);
    const float rstd = rsqrtf(var + 1e-5f);
    const float gm = gs[0], bt = bs[0];
    uint2 uo;
    uo.x = cvtpk(gm * (f.x - mu) * rstd + bt, gm * (f.y - mu) * rstd + bt);
    uo.y = cvtpk(gm * (f.z - mu) * rstd + bt, gm * (f.w - mu) * rstd + bt);
    *(uint2*)(out + (size_t)row * D_ + t * 4) = uo;
}

// ---------------------------------------------------------------------------
// GEMM 128x128, 2-barrier, 4 blocks/CU (proven: FFN2 ~82-90us, O-proj ~26us).
// Cross-block TLP hides the per-tile vmcnt(0) drain. ni-inner epilogue.
// RES: 0 none, 2 fp32. OUTF: 0 bf16, 1 fp32.
// ---------------------------------------------------------------------------
template <int RELU, int RES, int OUTF>
__global__ __launch_bounds__(256, 4) void gemm_bt(const u16* __restrict__ A,
                                                  const u16* __restrict__ W,
                                                  const u16* __restrict__ bias,
                                                  const void* __restrict__ res,
                                                  void* __restrict__ out,
                                                  int M, int N, int K) {
    __shared__ __align__(16) u16 As[128 * 64];
    __shared__ __align__(16) u16 Bs[128 * 64];
    const int t = threadIdx.x;
    const int lane = t & 63, w = t >> 6;
    const int wm = w >> 1, wn = w & 1;

    const int nx = N >> 7;
    const int gsz = nx << 3;
    const int id = blockIdx.x;
    const int grp = id / gsz;
    const int rem = id - grp * gsz;
    const int m0 = ((grp << 3) + (rem & 7)) << 7;
    const int n0 = (rem >> 3) << 7;

    f32x4 acc[4][4];
#pragma unroll
    for (int mi = 0; mi < 4; ++mi)
#pragma unroll
        for (int ni = 0; ni < 4; ++ni) acc[mi][ni] = (f32x4){0.f, 0.f, 0.f, 0.f};

    const int r8 = lane >> 3, s8 = lane & 7;
    const int cg = s8 ^ r8;
    const u16* Ag = A + (size_t)(m0 + w * 8 + r8) * K + cg * 8;
    const u16* Bg = W + (size_t)(n0 + w * 8 + r8) * K + cg * 8;
    const size_t rI = (size_t)32 * K;
    u16* Asd = &As[(w * 8) * 64];
    u16* Bsd = &Bs[(w * 8) * 64];

    const int c = lane & 15, g = lane >> 4;
    const u16* As_r = &As[(wm * 64 + c) * 64];
    const u16* Bs_r = &Bs[(wn * 64 + c) * 64];
    const int sl0 = (g ^ (c & 7)) * 8;
    const int sl1 = ((4 + g) ^ (c & 7)) * 8;

    for (int kt = 0; kt < K; kt += 64) {
        __syncthreads();
        gl2lds16(Ag, Asd);
        gl2lds16(Ag + rI, Asd + 32 * 64);
        gl2lds16(Ag + 2 * rI, Asd + 64 * 64);
        gl2lds16(Ag + 3 * rI, Asd + 96 * 64);
        gl2lds16(Bg, Bsd);
        gl2lds16(Bg + rI, Bsd + 32 * 64);
        gl2lds16(Bg + 2 * rI, Bsd + 64 * 64);
        gl2lds16(Bg + 3 * rI, Bsd + 96 * 64);
        Ag += 64; Bg += 64;
        __syncthreads();
#pragma unroll
        for (int kc = 0; kc < 2; ++kc) {
            const int sl = kc ? sl1 : sl0;
            bf16x8 af[4], bfr[4];
#pragma unroll
            for (int i = 0; i < 4; ++i) {
                af[i] = *(const bf16x8*)(As_r + i * 16 * 64 + sl);
                bfr[i] = *(const bf16x8*)(Bs_r + i * 16 * 64 + sl);
            }
#pragma unroll
            for (int mi = 0; mi < 4; ++mi)
#pragma unroll
                for (int ni = 0; ni < 4; ++ni)
                    acc[mi][ni] = __builtin_amdgcn_mfma_f32_16x16x32_bf16(af[mi], bfr[ni], acc[mi][ni], 0, 0, 0);
        }
    }

    const int qd = lane >> 4, cl = lane & 15;
    float bv[4];
#pragma unroll
    for (int ni = 0; ni < 4; ++ni)
        bv[ni] = bflo((u32)bias[n0 + wn * 64 + ni * 16 + cl]);
#pragma unroll
    for (int mi = 0; mi < 4; ++mi) {
#pragma unroll
        for (int j = 0; j < 4; ++j) {
            const int row = m0 + wm * 64 + mi * 16 + qd * 4 + j;
#pragma unroll
            for (int ni = 0; ni < 4; ++ni) {
                const int col = n0 + wn * 64 + ni * 16 + cl;
                float vv = acc[mi][ni][j] + bv[ni];
                if (RELU) vv = fmaxf(vv, 0.f);
                if (RES == 2) vv += ((const float*)res)[(size_t)row * N + col];
                if (OUTF == 1)
                    ((float*)out)[(size_t)row * N + col] = vv;
                else
                    ((u16*)out)[(size_t)row * N + col] = f2bf(vv);
            }
        }
    }
}

// ---------------------------------------------------------------------------
// GEMM 256x256, 2-PHASE counted-vmcnt pipeline (validated r6/r7/r9 config;
// r8's finer 4-subphase grain REGRESSED — do not re-split).
// 12 ds_read_b128 feed 32 MFMA per phase (0.375 reads/MFMA).
// Ledger: ph0 stages (kt+1).{A1,B1}[4] -> buf^1; ph1 stages (kt+2).{A0,B0}[4]
// -> buf[cur].kc0; tile-end vmcnt(4) == tile kt+1 fully landed. Tail vmcnt(0).
// Conflict-free slot XOR (r3): slot = chunk ^ ((row>>1)&3).
// ---------------------------------------------------------------------------
template <int RELU>
__global__ __launch_bounds__(512, 2) void gemm256(const u16* __restrict__ A,
                                                  const u16* __restrict__ W,
                                                  const u16* __restrict__ bias,
                                                  u16* __restrict__ out,
                                                  int M, int N, int K) {
    __shared__ __align__(16) u16 As[2][2][256 * 32];
    __shared__ __align__(16) u16 Bs[2][2][256 * 32];
    const int t = threadIdx.x;
    const int lane = t & 63, w = t >> 6;
    const int wm = w >> 2, wn = w & 3;

    const int nx = N >> 8;
    const int gsz = nx << 3;
    const int id = blockIdx.x;
    const int grp = id / gsz;
    const int rem = id - grp * gsz;
    const int m0 = ((grp << 3) + (rem & 7)) << 8;
    const int n0 = (rem >> 3) << 8;

    f32x4 acc[8][4];
#pragma unroll
    for (int mi = 0; mi < 8; ++mi)
#pragma unroll
        for (int ni = 0; ni < 4; ++ni) acc[mi][ni] = (f32x4){0.f, 0.f, 0.f, 0.f};

    const int vr = lane >> 2, vs = lane & 3;
    const int cgs = vs ^ ((vr >> 1) & 3);
    const u16* Asrc = A + (size_t)(m0 + w * 16 + vr) * K + cgs * 8;
    const u16* Bsrc = W + (size_t)(n0 + w * 16 + vr) * K + cgs * 8;
    const size_t rI = (size_t)128 * K;

    auto stageA = [&](int p, int kc, int tk) {
        u16* d = &As[p][kc][(w * 16) * 32];
        const u16* s = Asrc + (size_t)tk * 64 + kc * 32;
        gl2lds16(s, d);
        gl2lds16(s + rI, d + 128 * 32);
    };
    auto stageB = [&](int p, int kc, int tk) {
        u16* d = &Bs[p][kc][(w * 16) * 32];
        const u16* s = Bsrc + (size_t)tk * 64 + kc * 32;
        gl2lds16(s, d);
        gl2lds16(s + rI, d + 128 * 32);
    };

    const int c = lane & 15, g = lane >> 4;
    const int sx = (g ^ ((c >> 1) & 3)) << 3;

    const int nt = K >> 6;
    stageA(0, 0, 0); stageB(0, 0, 0);
    stageA(0, 1, 0); stageB(0, 1, 0);
    stageA(1, 0, 1); stageB(1, 0, 1);
    asm volatile("s_waitcnt vmcnt(4)" ::: "memory");
    __builtin_amdgcn_s_barrier();
    __builtin_amdgcn_sched_barrier(0);

    int cur = 0;
    for (int kt = 0; kt < nt; ++kt) {
        // ---- phase 0: kc = 0 ----
        {
            bf16x8 af[8], bfv[4];
            const u16* Ab = &As[cur][0][0];
            const u16* Bb = &Bs[cur][0][0];
#pragma unroll
            for (int i = 0; i < 8; ++i)
                af[i] = *(const bf16x8*)(Ab + (wm * 128 + i * 16 + c) * 32 + sx);
#pragma unroll
            for (int i = 0; i < 4; ++i)
                bfv[i] = *(const bf16x8*)(Bb + (wn * 64 + i * 16 + c) * 32 + sx);
            if (kt + 1 < nt) { stageA(cur ^ 1, 1, kt + 1); stageB(cur ^ 1, 1, kt + 1); }
            __builtin_amdgcn_s_barrier();
            __builtin_amdgcn_s_setprio(1);
#pragma unroll
            for (int mi = 0; mi < 8; ++mi)
#pragma unroll
                for (int ni = 0; ni < 4; ++ni)
                    acc[mi][ni] = __builtin_amdgcn_mfma_f32_16x16x32_bf16(
                        af[mi], bfv[ni], acc[mi][ni], 0, 0, 0);
            __builtin_amdgcn_s_setprio(0);
            __builtin_amdgcn_s_barrier();   // kc0 reads done -> ph1 may overwrite
            __builtin_amdgcn_sched_barrier(0);
        }
        // ---- phase 1: kc = 1 ----
        {
            bf16x8 af[8], bfv[4];
            const u16* Ab = &As[cur][1][0];
            const u16* Bb = &Bs[cur][1][0];
#pragma unroll
            for (int i = 0; i < 8; ++i)
                af[i] = *(const bf16x8*)(Ab + (wm * 128 + i * 16 + c) * 32 + sx);
#pragma unroll
            for (int i = 0; i < 4; ++i)
                bfv[i] = *(const bf16x8*)(Bb + (wn * 64 + i * 16 + c) * 32 + sx);
            if (kt + 2 < nt) { stageA(cur, 0, kt + 2); stageB(cur, 0, kt + 2); }
            __builtin_amdgcn_s_barrier();
            __builtin_amdgcn_s_setprio(1);
#pragma unroll
            for (int mi = 0; mi < 8; ++mi)
#pragma unroll
                for (int ni = 0; ni < 4; ++ni)
                    acc[mi][ni] = __builtin_amdgcn_mfma_f32_16x16x32_bf16(
                        af[mi], bfv[ni], acc[mi][ni], 0, 0, 0);
            __builtin_amdgcn_s_setprio(0);
        }
        // ---- tile end: certify tile kt+1 ----
        if (kt < nt - 2)
            asm volatile("s_waitcnt vmcnt(4)" ::: "memory");
        else
            asm volatile("s_waitcnt vmcnt(0)" ::: "memory");
        __builtin_amdgcn_s_barrier();
        __builtin_amdgcn_sched_barrier(0);
        cur ^= 1;
    }

    // epilogue: ni innermost -> full 128B line dirty in 4 consecutive stores
#pragma unroll
    for (int mi = 0; mi < 8; ++mi) {
#pragma unroll
        for (int j = 0; j < 4; ++j) {
            const int row = m0 + wm * 128 + mi * 16 + g * 4 + j;
#pragma unroll
            for (int ni = 0; ni < 4; ++ni) {
                const int col = n0 + wn * 64 + ni * 16 + c;
                float vv = acc[mi][ni][j] + bflo((u32)bias[col]);
                if (RELU) vv = fmaxf(vv, 0.f);
                out[(size_t)row * N + col] = f2bf(vv);
            }
        }
    }
}

// ---------------------------------------------------------------------------
// MFMA flash attention: exact r9 structure (QBLK=256, 2 blocks/CU — the
// 84.2us config) + round 17's head-colocating XCD swizzle. r10 postmortem:
// QBLK=128/8-blocks-per-head flipped the kernel HBM-bound (FETCH 73.8->216MB)
// because same-head blocks round-robin across XCD L2s. Now 1-D grid of 512:
// bid = (head%8) + 8*(qchunk + 4*(head/8)) -> all 4 q-chunks of a head share
// bid%8 (same XCD heuristic) and are near-consecutive (co-scheduled).
// Per-XCD K/V working set = 16 heads x 256KB = 4MB = one L2.
// ---------------------------------------------------------------------------
__global__ __launch_bounds__(256, 2) void attn_mfma(const u16* __restrict__ QKV,
                                                    u16* __restrict__ O) {
    __shared__ __align__(16) u16 lds[6 * 64 * 64];  // Ks | VsT | P x4 waves
    u16* Ks = lds;
    u16* VsT = lds + 64 * 64;

    const int t = threadIdx.x;
    const int lane = t & 63, w = t >> 6;
    u16* Pw = lds + (2 + w) * 64 * 64;
    // head-colocating swizzle decode
    const int xcd = blockIdx.x & 7;
    const int rem = blockIdx.x >> 3;
    const int qc = rem & 3;
    const int head = (rem >> 2) * 8 + xcd;   // 0..127
    const int b = head >> 4, h = head & 15;
    const int q_base = qc * 256 + w * 64;
    const int c = lane & 15, g = lane >> 4;
    const int c7 = c & 7;
    const float SC = 0.18033688011112042f;  // (1/8)*log2(e)

    bf16x8 qfrag[4][2];
#pragma unroll
    for (int ni = 0; ni < 4; ++ni)
#pragma unroll
        for (int kc = 0; kc < 2; ++kc)
            qfrag[ni][kc] = *(const bf16x8*)(QKV + (size_t)(b * S_ + q_base + 16 * ni + c) * LDQKV +
                                             h * 64 + kc * 32 + 8 * g);

    f32x4 acc_o[4][4];
#pragma unroll
    for (int mi = 0; mi < 4; ++mi)
#pragma unroll
        for (int ni = 0; ni < 4; ++ni) acc_o[mi][ni] = (f32x4){0.f, 0.f, 0.f, 0.f};
    float m_st[4] = {-1e30f, -1e30f, -1e30f, -1e30f};  // raw (unscaled) units
    float l_st[4] = {0.f, 0.f, 0.f, 0.f};

    const size_t kbase = (size_t)(b * S_) * LDQKV + 1024 + h * 64;
    const size_t vbase = (size_t)(b * S_) * LDQKV + 2048 + h * 64;

    const int r8 = lane >> 3, s8 = lane & 7;
    const int cgk = s8 ^ r8;
    const u16* Kg = QKV + kbase + (size_t)(w * 8 + r8) * LDQKV + cgk * 8;
    u16* Ksd = &Ks[(w * 8) * 64];
    const size_t rIk = (size_t)32 * LDQKV;

    const int vr = t >> 3, vdq = t & 7;
    const u16* Vg = QKV + vbase + (size_t)(2 * vr) * LDQKV + vdq * 8;

    int vfx[4];
#pragma unroll
    for (int mi = 0; mi < 4; ++mi) vfx[mi] = c7 ^ ((2 * mi + (c >> 3)) & 7);

    for (int kt = 0; kt < 16; ++kt) {
        __syncthreads();
        gl2lds16(Kg, Ksd);
        gl2lds16(Kg + rIk, Ksd + 32 * 64);
        Kg += (size_t)64 * LDQKV;
        {
            uint4 a = *(const uint4*)Vg;
            uint4 bb = *(const uint4*)(Vg + LDQKV);
            Vg += (size_t)64 * LDQKV;
            const u32 aw[4] = {a.x, a.y, a.z, a.w};
            const u32 bw[4] = {bb.x, bb.y, bb.z, bb.w};
#pragma unroll
            for (int i = 0; i < 8; ++i) {
                u32 wv;
                if (i & 1)
                    wv = (aw[i >> 1] >> 16) | (bw[i >> 1] & 0xffff0000u);
                else
                    wv = (aw[i >> 1] & 0xffffu) | (bw[i >> 1] << 16);
                const int d = vdq * 8 + i;
                *(u32*)&VsT[d * 64 + (((vr >> 2) ^ (i ^ vdq)) << 3) + ((vr & 3) << 1)] = wv;
            }
        }
        __syncthreads();

        f32x4 acc_s[4][4];
#pragma unroll
        for (int mi = 0; mi < 4; ++mi)
#pragma unroll
            for (int ni = 0; ni < 4; ++ni) acc_s[mi][ni] = (f32x4){0.f, 0.f, 0.f, 0.f};
        __builtin_amdgcn_s_setprio(1);
#pragma unroll
        for (int kc = 0; kc < 2; ++kc) {
            bf16x8 kf[4];
#pragma unroll
            for (int mi = 0; mi < 4; ++mi)
                kf[mi] = *(const bf16x8*)&Ks[(16 * mi + c) * 64 + (((kc * 4 + g) ^ c7) << 3)];
#pragma unroll
            for (int mi = 0; mi < 4; ++mi)
#pragma unroll
                for (int ni = 0; ni < 4; ++ni)
                    acc_s[mi][ni] = __builtin_amdgcn_mfma_f32_16x16x32_bf16(
                        kf[mi], qfrag[ni][kc], acc_s[mi][ni], 0, 0, 0);
        }
        __builtin_amdgcn_s_setprio(0);

        float alpha[4];
        bool resc[4];
#pragma unroll
        for (int ni = 0; ni < 4; ++ni) {
            float mx = -1e30f;
#pragma unroll
            for (int mi = 0; mi < 4; ++mi) {
#pragma unroll
                for (int j = 0; j < 4; ++j) mx = fmaxf(mx, acc_s[mi][ni][j]);
            }
            mx = fmaxf(mx, __shfl_xor(mx, 16, 64));
            mx = fmaxf(mx, __shfl_xor(mx, 32, 64));
            const float mo = m_st[ni];
            const float mn = fmaxf(mo, mx);
            resc[ni] = __any(mn > mo);
            if (resc[ni]) {
                alpha[ni] = exp2f((mo - mn) * SC);
                m_st[ni] = mn;
            } else {
                alpha[ni] = 1.f;
            }
            const float nms = m_st[ni] * SC;
            float sum = 0.f;
#pragma unroll
            for (int mi = 0; mi < 4; ++mi) {
                const float p0 = exp2f(fmaf(acc_s[mi][ni][0], SC, -nms));
                const float p1 = exp2f(fmaf(acc_s[mi][ni][1], SC, -nms));
                const float p2 = exp2f(fmaf(acc_s[mi][ni][2], SC, -nms));
                const float p3 = exp2f(fmaf(acc_s[mi][ni][3], SC, -nms));
                sum += (p0 + p1) + (p2 + p3);
                uint2 pk;
                pk.x = cvtpk(p0, p1);
                pk.y = cvtpk(p2, p3);
                *(uint2*)&Pw[(16 * ni + c) * 64 +
                             ((((2 * mi + (g >> 1)) ^ c7) << 3) + ((g & 1) << 2))] = pk;
            }
            sum += __shfl_xor(sum, 16, 64);
            sum += __shfl_xor(sum, 32, 64);
            l_st[ni] = (resc[ni] ? l_st[ni] * alpha[ni] : l_st[ni]) + sum;
        }
#pragma unroll
        for (int ni = 0; ni < 4; ++ni) {
            if (resc[ni]) {
#pragma unroll
                for (int mi = 0; mi < 4; ++mi) {
#pragma unroll
                    for (int j = 0; j < 4; ++j) acc_o[mi][ni][j] *= alpha[ni];
                }
            }
        }

        __builtin_amdgcn_s_setprio(1);
#pragma unroll
        for (int kc = 0; kc < 2; ++kc) {
            bf16x8 vf[4], pf[4];
#pragma unroll
            for (int mi = 0; mi < 4; ++mi)
                vf[mi] = *(const bf16x8*)&VsT[(16 * mi + c) * 64 + (((kc * 4 + g) ^ vfx[mi]) << 3)];
#pragma unroll
            for (int ni = 0; ni < 4; ++ni)
                pf[ni] = *(const bf16x8*)&Pw[(16 * ni + c) * 64 + (((kc * 4 + g) ^ c7) << 3)];
#pragma unroll
            for (int mi = 0; mi < 4; ++mi)
#pragma unroll
                for (int ni = 0; ni < 4; ++ni)
                    acc_o[mi][ni] = __builtin_amdgcn_mfma_f32_16x16x32_bf16(
                        vf[mi], pf[ni], acc_o[mi][ni], 0, 0, 0);
        }
        __builtin_amdgcn_s_setprio(0);
    }

#pragma unroll
    for (int ni = 0; ni < 4; ++ni) {
        const float inv_l = 1.f / l_st[ni];
        u16* op = O + (size_t)(b * S_ + q_base + 16 * ni + c) * D_ + h * 64;
#pragma unroll
        for (int mi = 0; mi < 4; ++mi) {
            uint2 uo;
            uo.x = cvtpk(acc_o[mi][ni][0] * inv_l, acc_o[mi][ni][1] * inv_l);
            uo.y = cvtpk(acc_o[mi][ni][2] * inv_l, acc_o[mi][ni][3] * inv_l);
            *(uint2*)(op + 16 * mi + 4 * g) = uo;
        }
    }
}

// ---------------------------------------------------------------------------
extern "C" void kernel_launch(void* const* d_in, const int* in_sizes, int n_in,
                              void* d_out, int out_size, void* d_ws, size_t ws_size,
                              hipStream_t stream) {
    (void)in_sizes; (void)n_in; (void)out_size; (void)ws_size;
    char* ws = (char*)d_ws;
    const size_t MB = 1ull << 20;
    const size_t KB = 1024;
    u16* wqkv = (u16*)(ws + 16 * MB);       // 6 MB  [3072][1024]
    u16* won  = (u16*)(ws + 22 * MB);       // 2 MB
    u16* w1n  = (u16*)(ws + 24 * MB);       // 8 MB
    u16* w2n  = (u16*)(ws + 32 * MB);       // 8 MB
    u16* bqkv = (u16*)(ws + 40 * MB);       // 6 KB
    u16* bon  = (u16*)(ws + 40 * MB + 64 * KB);
    u16* b1n  = (u16*)(ws + 40 * MB + 128 * KB);
    u16* b2n  = (u16*)(ws + 40 * MB + 192 * KB);
    u16* h1   = (u16*)(ws + 48 * MB);       // 16 MB: ln1 out; attn out
    u16* qkv  = (u16*)(ws + 64 * MB);       // 48 MB: fused QKV
    float* x2 = (float*)(ws + 64 * MB);     // 32 MB, overlays qkv (dead after attn)
    u16* h2   = (u16*)(ws + 96 * MB);       // 16 MB, overlays qkv tail
    u16* f1   = (u16*)(ws + 112 * MB);      // 64 MB -> total 176 MB

    const int M = B_ * S_;  // 8192
    const int CONV_BLOCKS = 2048;

    // prep: LN1 (M blocks) + all 12 fp32->bf16 conversions (grid-strided)
    {
        PrepTbl tb;
        tb.src[0]  = d_in[2];  tb.dst[0]  = wqkv;               tb.nch[0]  = D_ * D_ / 8;
        tb.src[1]  = d_in[4];  tb.dst[1]  = wqkv + D_ * D_;     tb.nch[1]  = D_ * D_ / 8;
        tb.src[2]  = d_in[6];  tb.dst[2]  = wqkv + 2 * D_ * D_; tb.nch[2]  = D_ * D_ / 8;
        tb.src[3]  = d_in[8];  tb.dst[3]  = won;                tb.nch[3]  = D_ * D_ / 8;
        tb.src[4]  = d_in[10]; tb.dst[4]  = w1n;                tb.nch[4]  = DFF_ * D_ / 8;
        tb.src[5]  = d_in[12]; tb.dst[5]  = w2n;                tb.nch[5]  = D_ * DFF_ / 8;
        tb.src[6]  = d_in[3];  tb.dst[6]  = bqkv;               tb.nch[6]  = D_ / 8;
        tb.src[7]  = d_in[5];  tb.dst[7]  = bqkv + D_;          tb.nch[7]  = D_ / 8;
        tb.src[8]  = d_in[7];  tb.dst[8]  = bqkv + 2 * D_;      tb.nch[8]  = D_ / 8;
        tb.src[9]  = d_in[9];  tb.dst[9]  = bon;                tb.nch[9]  = D_ / 8;
        tb.src[10] = d_in[11]; tb.dst[10] = b1n;                tb.nch[10] = DFF_ / 8;
        tb.src[11] = d_in[13]; tb.dst[11] = b2n;                tb.nch[11] = D_ / 8;
        tb.total = (4 * D_ * D_ + 2 * DFF_ * D_ + 5 * D_ + DFF_) / 8;
        tb.convBlocks = CONV_BLOCKS;
        prep_kernel<<<M + CONV_BLOCKS, 256, 0, stream>>>(
            tb, (const float*)d_in[0], (const float*)d_in[14],
            (const float*)d_in[15], h1);
    }

    // QKV: 256^2 2-phase pipeline (grid 384)
    gemm256<0><<<(LDQKV / 256) * (M / 256), 512, 0, stream>>>(h1, wqkv, bqkv, qkv, M, LDQKV, D_);
    // attn: 1-D grid 512, head-colocating XCD swizzle
    attn_mfma<<<512, 256, 0, stream>>>(qkv, h1);
    // O-proj: residual = original x (fp32), fp32 out
    gemm_bt<0, 2, 1><<<(D_ / 128) * (M / 128), 256, 0, stream>>>(h1, won, bon, d_in[0], x2, M, D_, D_);
    ln_kernel<<<M, 256, 0, stream>>>(x2, (const float*)d_in[16], (const float*)d_in[17], h2);
    gemm256<1><<<(DFF_ / 256) * (M / 256), 512, 0, stream>>>(h2, w1n, b1n, f1, M, DFF_, D_);
    gemm_bt<0, 2, 1><<<(D_ / 128) * (M / 128), 256, 0, stream>>>(f1, w2n, b2n, x2, d_out, M, D_, DFF_);
}